// Round 1
// baseline (657.414 us; speedup 1.0000x reference)
//
#include <hip/hip_runtime.h>
#include <math.h>

#define T_DATA 50000
#define SUB_NO 20
#define T_NO 200
#define N_BASIS 20

// workspace float offsets
#define WS_E    0          // (T,20) e synapse sums
#define WS_I    1000000    // (T,20) i synapse sums
#define WS_EKT  2000000    // (200,20) e_kern transposed (tau-major)
#define WS_IKT  2004000    // (200,20) i_kern transposed
#define WS_WSE  2008400    // (20,20) Cd[s][c] * W_sub[c]^2
#define WS_HF   2008800    // (T) hist_filt

#define KA_RED_BLOCKS 977    // 977*256 = 250112 >= 250000 = T_DATA*5 (t,sg) threads
#define KA_HIST_BLOCKS 196   // 196*256 = 50176 >= 50000 t threads
#define KA_TOTAL (KA_RED_BLOCKS + 1 + KA_HIST_BLOCKS)

__device__ __forceinline__ float lrelu(float x) { return x > 0.f ? x : 0.01f * x; }

// ---------------- Kernel A ----------------
// blocks [0,977):    syn_agg[t][4sg..4sg+3] = sum_{g} S[t] float4s (thread=(t,sg))
// block 977:         basis matmuls -> ws kernels + out_filters, Cd*W_sub^2
// blocks [978,1174): hist+spike causal convs (lag 1) -> final_V, ws hist_filt
__global__ __launch_bounds__(256) void kA(const float* __restrict__ Se,
                                          const float* __restrict__ Si,
                                          const float* __restrict__ Z,
                                          const int* __restrict__ C_den,
                                          const float* __restrict__ cb,
                                          const float* __restrict__ W_syn,
                                          const float* __restrict__ W_hist,
                                          const float* __restrict__ W_sub,
                                          const float* __restrict__ W_spk,
                                          const float* __restrict__ Tau,
                                          const float* __restrict__ Vo,
                                          float* __restrict__ ws,
                                          float* __restrict__ out) {
    int tid = threadIdx.x;
    int bid = blockIdx.x;

    if (bid < KA_RED_BLOCKS) {
        int gid = bid * 256 + tid;
        if (gid >= T_DATA * 5) return;
        int t = gid / 5, sg = gid % 5;
        const float4* Se4 = (const float4*)Se;   // row = 500 float4
        const float4* Si4 = (const float4*)Si;   // row = 125 float4

        float4 a = make_float4(0.f, 0.f, 0.f, 0.f);
        int base_e = t * 500 + sg;
        #pragma unroll 10
        for (int g = 0; g < 100; g++) {
            float4 v = Se4[base_e + g * 5];
            a.x += v.x; a.y += v.y; a.z += v.z; a.w += v.w;
        }
        float4 b = make_float4(0.f, 0.f, 0.f, 0.f);
        int base_i = t * 125 + sg;
        #pragma unroll
        for (int g = 0; g < 25; g++) {
            float4 v = Si4[base_i + g * 5];
            b.x += v.x; b.y += v.y; b.z += v.z; b.w += v.w;
        }
        ((float4*)(ws + WS_E))[t * 5 + sg] = a;
        ((float4*)(ws + WS_I))[t * 5 + sg] = b;
        return;
    }

    if (bid == KA_RED_BLOCKS) {
        for (int j = tid; j < 4000; j += 256) {
            int s = j / 200, tau = j % 200;
            float se = 0.f, si = 0.f;
            #pragma unroll
            for (int b = 0; b < N_BASIS; b++) {
                float c = cb[b * 200 + tau];
                se += W_syn[(s * N_BASIS + b) * 2 + 0] * c;
                si += W_syn[(s * N_BASIS + b) * 2 + 1] * c;
            }
            ws[WS_EKT + tau * 20 + s] = se;
            ws[WS_IKT + tau * 20 + s] = si;
            out[2 * T_DATA + j] = se;           // e_kern rows 0..19
            out[2 * T_DATA + 4000 + j] = si;    // i_kern rows 20..39
        }
        for (int j = tid; j < 200; j += 256) {
            float h = 0.f;
            #pragma unroll
            for (int b = 0; b < N_BASIS; b++) h += W_hist[b] * cb[b * 200 + j];
            out[2 * T_DATA + 8000 + j] = h;     // hist_kern row 40
        }
        for (int j = tid; j < 400; j += 256) {
            int c = j % 20;
            ws[WS_WSE + j] = (float)C_den[j] * W_sub[c] * W_sub[c];
        }
        return;
    }

    // ---- hist + spike convs ----
    __shared__ float z[456];        // 256 t + 200 halo
    __shared__ float2 hk[200];      // (hist_kern, spk_kern)
    int t0 = (bid - KA_RED_BLOCKS - 1) * 256;
    for (int f = tid; f < 456; f += 256) {
        int u = t0 - 200 + f;
        z[f] = (u >= 0 && u < T_DATA) ? Z[u] : 0.f;
    }
    if (tid < 200) {
        float h = 0.f;
        #pragma unroll
        for (int b = 0; b < N_BASIS; b++) h += W_hist[b] * cb[b * 200 + tid];
        float tau2 = Tau[0] * Tau[0];
        float tt = (float)tid / tau2;
        float sk = tt * expf(-tt) * W_spk[0] * W_spk[0];
        hk[tid] = make_float2(h, sk);
    }
    __syncthreads();
    float ha = 0.f, sa = 0.f;
    #pragma unroll 4
    for (int tau = 0; tau < T_NO; tau++) {
        float zv = z[tid + 199 - tau];   // Z[t-1-tau]
        float2 hv = hk[tau];             // uniform -> broadcast
        ha += zv * hv.x;
        sa += zv * hv.y;
    }
    int t = t0 + tid;
    if (t < T_DATA) {
        out[t] = sa + Vo[0];             // final_V
        ws[WS_HF + t] = ha;              // hist_filt for kB root
    }
}

// ---------------- Kernel B: grouped conv + subunit tree + MLPs -------------
__device__ __forceinline__ float sub_mlp(int s, float x,
                                         const float* __restrict__ w1,
                                         const float* __restrict__ w2,
                                         const float* __restrict__ w3,
                                         const float* __restrict__ w4) {
    float h1[5], h2[5], h3[5];
    #pragma unroll
    for (int k = 0; k < 5; k++) h1[k] = lrelu(x * w1[s * 5 + k]);
    #pragma unroll
    for (int j = 0; j < 5; j++) {
        float v = 0.f;
        #pragma unroll
        for (int k = 0; k < 5; k++) v += h1[k] * w2[s * 25 + k * 5 + j];
        h2[j] = lrelu(v);
    }
    #pragma unroll
    for (int j = 0; j < 5; j++) {
        float v = 0.f;
        #pragma unroll
        for (int k = 0; k < 5; k++) v += h2[k] * w3[s * 25 + k * 5 + j];
        h3[j] = lrelu(v);
    }
    float o = 0.f;
    #pragma unroll
    for (int k = 0; k < 5; k++) o += h3[k] * w4[k * 20 + s];
    return o;
}

#define KB_X 64
#define KB_T 256             // t per block (4 consecutive per x-thread)
#define KB_ROWS 455          // KB_T + 199
#define KB_SRP 115           // padded sub-plane rows (ceil(455/4)+1)
#define KB_THREADS 640       // (64, 5, 2): 10 waves, z = tau half

// block = (64, 5, 2): wave w has uniform (sg, z). Thread x owns t = t0+4x..4x+3.
// z=0 handles taus 0..99, z=1 handles taus 100..199 (partial accs summed in
// the LDS exchange) -> 2x waves/SIMD AND half the serial tau chain.
// Sliding window: per tau only ONE new row per array enters (row%4 is
// lane-invariant), so tile is split into 4 row%4 sub-planes; in-loop reads
// are lane-consecutive float4 (conflict-free). e/i kernels staged in LDS
// (broadcast reads) instead of per-tau global loads.
// LDS = 73600 (tile) + 32000 (kernels) = 105600 B -> 1 block/CU, 10 waves.
__global__ __launch_bounds__(KB_THREADS) void kB(const float* __restrict__ ws,
                                                 const float* __restrict__ Theta,
                                                 const float* __restrict__ w1,
                                                 const float* __restrict__ w2,
                                                 const float* __restrict__ w3,
                                                 const float* __restrict__ w4,
                                                 float* __restrict__ out) {
    __shared__ float4 tile[2 * 5 * 4 * KB_SRP];    // [arr][sg][row%4][row/4]
    __shared__ float4 hkE[1000];                   // [tau][5] e_kern
    __shared__ float4 hkI[1000];                   // [tau][5] i_kern
    int x = threadIdx.x;    // 0..63
    int sg = __builtin_amdgcn_readfirstlane(threadIdx.y);  // 0..4
    int z  = __builtin_amdgcn_readfirstlane(threadIdx.z);  // 0..1 (tau half)
    int t0 = blockIdx.x * KB_T;
    int lin = x + 64 * sg + 320 * z;

    // stage rows t0-199 .. t0+255 of ws_E / ws_I into row%4 sub-planes
    const float4* wsE4 = (const float4*)(ws + WS_E);
    const float4* wsI4 = (const float4*)(ws + WS_I);
    long gbase = (long)(t0 - 199) * 5;
    for (int f = lin; f < KB_ROWS * 5; f += KB_THREADS) {
        long g = gbase + f;            // consecutive f -> coalesced global
        int row = f / 5, gg = f % 5;
        int sub = row & 3, idx = row >> 2;
        float4 ve = make_float4(0.f, 0.f, 0.f, 0.f);
        float4 vi = ve;
        if (g >= 0 && g < (long)T_DATA * 5) {
            ve = wsE4[g];
            vi = wsI4[g];
        }
        tile[((0 * 5 + gg) * 4 + sub) * KB_SRP + idx] = ve;
        tile[((1 * 5 + gg) * 4 + sub) * KB_SRP + idx] = vi;
    }
    // stage filter kernels (tau-major [tau][5] float4)
    const float4* eK = (const float4*)(ws + WS_EKT);
    const float4* iK = (const float4*)(ws + WS_IKT);
    for (int f = lin; f < 1000; f += KB_THREADS) {
        hkE[f] = eK[f];
        hkI[f] = iK[f];
    }
    __syncthreads();

    const float4* te = &tile[(0 * 5 + sg) * 4 * KB_SRP];
    const float4* ti = &tile[(1 * 5 + sg) * 4 * KB_SRP];

    float4 we[4], wi[4], acc[4];
    #pragma unroll
    for (int j = 0; j < 4; j++) acc[j] = make_float4(0.f, 0.f, 0.f, 0.f);
    // prologue: slots 0..2 hold rows 4x+200-100z .. 4x+202-100z (idx x+50-25z)
    int idx0 = x + 50 - 25 * z;
    we[0] = te[0 * KB_SRP + idx0]; wi[0] = ti[0 * KB_SRP + idx0];
    we[1] = te[1 * KB_SRP + idx0]; wi[1] = ti[1 * KB_SRP + idx0];
    we[2] = te[2 * KB_SRP + idx0]; wi[2] = ti[2 * KB_SRP + idx0];

    int m0 = 25 * z;
    for (int mm = 0; mm < 25; mm++) {
        int m = m0 + mm;
        int idx = x + 49 - m;          // (4x + 199-tau)/4, same for p=0..3
        #pragma unroll
        for (int p = 0; p < 4; p++) {
            int tau = 4 * m + p;
            const int s0 = (3 - p) & 3;          // slot of entering row
            we[s0] = te[s0 * KB_SRP + idx];      // row 4x + 199 - tau
            wi[s0] = ti[s0 * KB_SRP + idx];
            float4 ke = hkE[tau * 5 + sg];       // wave-uniform -> broadcast
            float4 ki = hkI[tau * 5 + sg];
            #pragma unroll
            for (int j = 0; j < 4; j++) {        // t = t0 + 4x + j
                const int sl = (s0 + j) & 3;     // slot of row t - tau
                acc[j].x += we[sl].x * ke.x + wi[sl].x * ki.x;
                acc[j].y += we[sl].y * ke.y + wi[sl].y * ki.y;
                acc[j].z += we[sl].z * ke.z + wi[sl].z * ki.z;
                acc[j].w += we[sl].w * ke.w + wi[sl].w * ki.w;
            }
        }
    }

    // exchange: accP[z][sg][j][x] partial accs for t_local = 4x + j
    __syncthreads();
    float4* accP = tile;   // reuse: 2*5*4*64 = 2560 float4 <= 4600
    #pragma unroll
    for (int j = 0; j < 4; j++) accP[((z * 20) + sg * 4 + j) * 64 + x] = acc[j];
    __syncthreads();

    if (lin >= 256) return;
    // reader thread: wave w = lin>>6 (0..3), lane xr = lin&63
    int w = lin >> 6, xr = lin & 63;
    int t = t0 + 4 * xr + w;
    if (t >= T_DATA) return;

    float acc20[20];
    #pragma unroll
    for (int g = 0; g < 5; g++) {
        float4 v0 = accP[(g * 4 + w) * 64 + xr];          // z=0 partial
        float4 v1 = accP[(20 + g * 4 + w) * 64 + xr];     // z=1 partial
        acc20[g * 4 + 0] = v0.x + v1.x; acc20[g * 4 + 1] = v0.y + v1.y;
        acc20[g * 4 + 2] = v0.z + v1.z; acc20[g * 4 + 3] = v0.w + v1.w;
    }
    const float* wse = ws + WS_WSE;
    float ns[20];
    #pragma unroll
    for (int s = 0; s < 20; s++) ns[s] = 0.f;
    #pragma unroll
    for (int si = 19; si >= 1; si--) {
        float ag = 0.f;
        #pragma unroll
        for (int c = 0; c < 20; c++) ag += wse[si * 20 + c] * ns[c];
        float xx = lrelu(acc20[si] + Theta[si] + ag);
        ns[si] = sub_mlp(si, xx, w1, w2, w3, w4);
    }
    float ag0 = 0.f;
    #pragma unroll
    for (int c = 0; c < 20; c++) ag0 += wse[c] * ns[c];
    float x0 = lrelu(ws[WS_HF + t] + acc20[0] + ag0 + Theta[0]);
    float zf = sub_mlp(0, x0, w1, w2, w3, w4);
    out[T_DATA + t] = 1.f / (1.f + expf(-zf));    // final_Z
}

extern "C" void kernel_launch(void* const* d_in, const int* in_sizes, int n_in,
                              void* d_out, int out_size, void* d_ws, size_t ws_size,
                              hipStream_t stream) {
    const float* S_e    = (const float*)d_in[0];
    const float* S_i    = (const float*)d_in[1];
    const float* Z      = (const float*)d_in[2];
    const int*   C_den  = (const int*)d_in[3];
    // d_in[4], d_in[5]: C_syn_e / C_syn_i — one-hot j -> j%20, exploited in kA
    const float* cb     = (const float*)d_in[6];
    const float* W_syn  = (const float*)d_in[7];
    const float* W_hist = (const float*)d_in[8];
    const float* W_sub  = (const float*)d_in[9];
    const float* W_spk  = (const float*)d_in[10];
    const float* Tau    = (const float*)d_in[11];
    const float* V_o    = (const float*)d_in[12];
    const float* Theta  = (const float*)d_in[13];
    const float* w1     = (const float*)d_in[14];
    const float* w2     = (const float*)d_in[15];
    const float* w3     = (const float*)d_in[16];
    const float* w4     = (const float*)d_in[17];
    float* out = (float*)d_out;
    float* ws  = (float*)d_ws;

    kA<<<KA_TOTAL, 256, 0, stream>>>(S_e, S_i, Z, C_den, cb, W_syn, W_hist,
                                     W_sub, W_spk, Tau, V_o, ws, out);
    dim3 b3(KB_X, 5, 2);
    kB<<<(T_DATA + KB_T - 1) / KB_T, b3, 0, stream>>>(
        ws, Theta, w1, w2, w3, w4, out);
}